// Round 6
// baseline (508.781 us; speedup 1.0000x reference)
//
#include <hip/hip_runtime.h>
#include <math.h>
#include <float.h>
#include <limits.h>
#include <stdint.h>

namespace {

constexpr int B  = 2;
constexpr int CK = 64;
constexpr int N  = 12960;   // T*H*W
constexpr int M  = 1620;    // H*W
constexpr int CV = 384;
constexpr int K  = 20;

constexpr int MT     = 16;                    // m per phase-1 block
constexpr int SEG    = 512;                   // n per segment (LDS-resident)
constexpr int NSEG   = (N + SEG - 1) / SEG;   // 26 (last segment = 192)
constexpr int MTILES = (M + MT - 1) / MT;     // 102 (last tile: 4 real m)
constexpr int CAP    = 64;                    // candidate cap per (m,seg)
constexpr int HP     = 132;                   // padded 128-bin histogram row

// monotone float->uint key (order-preserving)
__device__ __forceinline__ uint32_t f2k(float x) {
  uint32_t u = __float_as_uint(x);
  return u ^ ((u & 0x80000000u) ? 0xFFFFFFFFu : 0x80000000u);
}

// [C][N] -> [N][C] transpose
__global__ __launch_bounds__(256) void transpose_in_kernel(const float* __restrict__ src,
                                                           float* __restrict__ dst, int C) {
  __shared__ float tile[64][65];
  int b = blockIdx.z;
  int n0 = blockIdx.x * 64;
  int c0 = blockIdx.y * 64;
  int tx = threadIdx.x & 63, ty = threadIdx.x >> 6;
  for (int r = ty; r < 64; r += 4) {
    int c = c0 + r, n = n0 + tx;
    tile[r][tx] = (n < N) ? src[((size_t)b * C + c) * N + n] : 0.f;
  }
  __syncthreads();
  for (int r = ty; r < 64; r += 4) {
    int n = n0 + r, c = c0 + tx;
    if (n < N) dst[((size_t)b * N + n) * C + c] = tile[tx][r];
  }
}

// out[b][c][m] = outT[b][m][c]
__global__ __launch_bounds__(256) void transpose_out_kernel(const float* __restrict__ outT,
                                                            float* __restrict__ out) {
  __shared__ float tile[64][65];
  int b = blockIdx.z;
  int m0 = blockIdx.x * 64;
  int c0 = blockIdx.y * 64;
  int tx = threadIdx.x & 63, ty = threadIdx.x >> 6;
  for (int r = ty; r < 64; r += 4) {
    int m = m0 + r;
    if (m < M) tile[r][tx] = outT[((size_t)b * M + m) * CV + c0 + tx];
  }
  __syncthreads();
  for (int r = ty; r < 64; r += 4) {
    int c = c0 + r, m = m0 + tx;
    if (m < M) out[((size_t)b * CV + c) * M + m] = tile[tx][r];
  }
}

// a_sq[b,n] = sum_c mk[b,c,n]^2
__global__ __launch_bounds__(256) void asq_kernel(const float* __restrict__ mk,
                                                  float* __restrict__ asq) {
  int i = blockIdx.x * 256 + threadIdx.x;
  if (i >= B * N) return;
  int b = i / N, n = i - b * N;
  const float* p = mk + (size_t)b * CK * N + n;
  float s = 0.f;
#pragma unroll
  for (int c = 0; c < CK; ++c) {
    float v = p[(size_t)c * N];
    s += v * v;
  }
  asq[i] = s;
}

// Phase 1: fused affinity + exact per-(m,segment) top-20. NOTHING N-sized
// touches global memory: the 16m x 512n fp32 tile lives in LDS; 2-pass
// (7+7 bit) radix finds thr; candidates (>= thr, incl. boundary ties) get
// exact 20-round lexicographic selection. Same c-ascending FMA chain as all
// prior passing rounds -> bit-identical affinities -> identical selection.
__global__ __launch_bounds__(512, 4) void aff_seg_select_kernel(
    const float* __restrict__ mk, const float* __restrict__ qk,
    const float* __restrict__ asq, float* __restrict__ gcv,
    int* __restrict__ gci) {
  const int b = blockIdx.z, sg = blockIdx.y, mt = blockIdx.x;
  const int mbase = mt * MT;
  const int nseg0 = sg * SEG;
  const int segLen = min(SEG, N - nseg0);
  const int t = threadIdx.x;

  __shared__ float affL[MT][SEG];        // 32 KB
  __shared__ float qs[CK][MT + 4];       // 5 KB, row 80 B (16B-aligned)
  __shared__ int hist[MT][HP];           // 8.25 KB, row skew 4 banks
  __shared__ int sh_d0[MT], sh_before[MT];
  __shared__ uint32_t sh_thr[MT];
  __shared__ int cnt[MT];
  __shared__ float cbv[MT][CAP];
  __shared__ int cbn[MT][CAP];

  // stage qk tile (zero-pad m tail)
  for (int l = t; l < CK * MT; l += 512) {
    int c = l >> 4, ml = l & 15;
    int mg = mbase + ml;
    qs[c][ml] = (mg < M) ? qk[((size_t)b * CK + c) * M + mg] : 0.f;
  }
  // pad tail segment columns with -FLT_MAX (key below every real affinity)
  if (segLen < SEG) {
    for (int l = t; l < MT * SEG; l += 512) {
      int mm = l >> 9, col = l & (SEG - 1);
      if (col >= segLen) affL[mm][col] = -FLT_MAX;
    }
  }
  __syncthreads();

  // ---- compute: thread = (n-float4 group g, 4 consecutive m) ----
  {
    const int g = t & 127;
    const int mj = (t >> 7) * 4;  // wave-uniform -> qs float4 broadcast
    const int nl = 4 * g;
    if (nl < segLen) {
      const int n0 = nseg0 + nl;
      const float* mkb = mk + (size_t)b * CK * N + n0;
      float4 a0 = make_float4(0.f, 0.f, 0.f, 0.f), a1 = a0, a2 = a0, a3 = a0;
#pragma unroll 4
      for (int c = 0; c < CK; ++c) {
        const float4 kv = *reinterpret_cast<const float4*>(mkb + (size_t)c * N);
        const float4 qv = *reinterpret_cast<const float4*>(&qs[c][mj]);
        a0.x += kv.x * qv.x; a0.y += kv.y * qv.x; a0.z += kv.z * qv.x; a0.w += kv.w * qv.x;
        a1.x += kv.x * qv.y; a1.y += kv.y * qv.y; a1.z += kv.z * qv.y; a1.w += kv.w * qv.y;
        a2.x += kv.x * qv.z; a2.y += kv.y * qv.z; a2.z += kv.z * qv.z; a2.w += kv.w * qv.z;
        a3.x += kv.x * qv.w; a3.y += kv.y * qv.w; a3.z += kv.z * qv.w; a3.w += kv.w * qv.w;
      }
      const float4 sq = *reinterpret_cast<const float4*>(asq + (size_t)b * N + n0);
      float4 accs[4] = {a0, a1, a2, a3};
#pragma unroll
      for (int j = 0; j < 4; ++j) {
        float4 r;
        r.x = (2.f * accs[j].x - sq.x) * 0.125f;
        r.y = (2.f * accs[j].y - sq.y) * 0.125f;
        r.z = (2.f * accs[j].z - sq.z) * 0.125f;
        r.w = (2.f * accs[j].w - sq.w) * 0.125f;
        *reinterpret_cast<float4*>(&affL[mj + j][nl]) = r;
      }
    }
  }
  __syncthreads();

  // ---- selection: thread group = (m_ = t>>5, s = t&31), 32 lanes per m ----
  const int m_ = t >> 5, s = t & 31;
  for (int l = t; l < MT * HP; l += 512) ((int*)hist)[l] = 0;
  if (s == 0) cnt[m_] = 0;
  __syncthreads();

  // pass 0: top 7 bits of monotone key
#pragma unroll
  for (int j = 0; j < 4; ++j) {
    const float4 v = *reinterpret_cast<const float4*>(&affL[m_][4 * (32 * j + s)]);
    atomicAdd(&hist[m_][f2k(v.x) >> 25], 1);
    atomicAdd(&hist[m_][f2k(v.y) >> 25], 1);
    atomicAdd(&hist[m_][f2k(v.z) >> 25], 1);
    atomicAdd(&hist[m_][f2k(v.w) >> 25], 1);
  }
  __syncthreads();
  {  // crossing digit: lane s owns bins 4s..4s+3 (ascending)
    int4 g4 = *reinterpret_cast<int4*>(&hist[m_][4 * s]);
    int sl = g4.x + g4.y + g4.z + g4.w;
    int sfx = sl;
#pragma unroll
    for (int off = 1; off < 32; off <<= 1) {
      int o = __shfl_down(sfx, off);
      sfx += (s + off < 32) ? o : 0;
    }
    int above = sfx - sl;
    if (above < K && K <= sfx) {
      int cum = above, ds;
      if (cum + g4.w >= K) ds = 3;
      else { cum += g4.w;
        if (cum + g4.z >= K) ds = 2;
        else { cum += g4.z;
          if (cum + g4.y >= K) ds = 1;
          else { cum += g4.y; ds = 0; } } }
      sh_d0[m_] = 4 * s + ds;
      sh_before[m_] = cum;
    }
  }
  __syncthreads();
  for (int l = t; l < MT * HP; l += 512) ((int*)hist)[l] = 0;
  __syncthreads();

  // pass 1: next 7 bits within the boundary digit
  const uint32_t d0 = (uint32_t)sh_d0[m_];
#pragma unroll
  for (int j = 0; j < 4; ++j) {
    const float4 v = *reinterpret_cast<const float4*>(&affL[m_][4 * (32 * j + s)]);
    uint32_t kk;
    kk = f2k(v.x); if ((kk >> 25) == d0) atomicAdd(&hist[m_][(kk >> 18) & 127], 1);
    kk = f2k(v.y); if ((kk >> 25) == d0) atomicAdd(&hist[m_][(kk >> 18) & 127], 1);
    kk = f2k(v.z); if ((kk >> 25) == d0) atomicAdd(&hist[m_][(kk >> 18) & 127], 1);
    kk = f2k(v.w); if ((kk >> 25) == d0) atomicAdd(&hist[m_][(kk >> 18) & 127], 1);
  }
  __syncthreads();
  {
    const int rem = K - sh_before[m_];  // 1..K
    int4 g4 = *reinterpret_cast<int4*>(&hist[m_][4 * s]);
    int sl = g4.x + g4.y + g4.z + g4.w;
    int sfx = sl;
#pragma unroll
    for (int off = 1; off < 32; off <<= 1) {
      int o = __shfl_down(sfx, off);
      sfx += (s + off < 32) ? o : 0;
    }
    int above = sfx - sl;
    if (above < rem && rem <= sfx) {
      int cum = above, ds;
      if (cum + g4.w >= rem) ds = 3;
      else { cum += g4.w;
        if (cum + g4.z >= rem) ds = 2;
        else { cum += g4.z;
          if (cum + g4.y >= rem) ds = 1;
          else { cum += g4.y; ds = 0; } } }
      sh_thr[m_] = (d0 << 25) | ((uint32_t)(4 * s + ds) << 18);
    }
  }
  __syncthreads();

  // collect candidates >= thr (count >= 20 by construction; ties ~1-3)
  const uint32_t thr = sh_thr[m_];
#pragma unroll
  for (int j = 0; j < 4; ++j) {
    const float4 v = *reinterpret_cast<const float4*>(&affL[m_][4 * (32 * j + s)]);
    const int nb = nseg0 + 4 * (32 * j + s);
    if (f2k(v.x) >= thr) { int q = atomicAdd(&cnt[m_], 1); if (q < CAP) { cbv[m_][q] = v.x; cbn[m_][q] = nb; } }
    if (f2k(v.y) >= thr) { int q = atomicAdd(&cnt[m_], 1); if (q < CAP) { cbv[m_][q] = v.y; cbn[m_][q] = nb + 1; } }
    if (f2k(v.z) >= thr) { int q = atomicAdd(&cnt[m_], 1); if (q < CAP) { cbv[m_][q] = v.z; cbn[m_][q] = nb + 2; } }
    if (f2k(v.w) >= thr) { int q = atomicAdd(&cnt[m_], 1); if (q < CAP) { cbv[m_][q] = v.w; cbn[m_][q] = nb + 3; } }
  }
  __syncthreads();

  // exact top-20 of candidates (v desc, n asc), sorted output
  const int nc = min(cnt[m_], CAP);
  float v0 = (s < nc) ? cbv[m_][s] : -FLT_MAX;
  int   i0 = (s < nc) ? cbn[m_][s] : INT_MAX;
  float v1 = (s + 32 < nc) ? cbv[m_][s + 32] : -FLT_MAX;
  int   i1 = (s + 32 < nc) ? cbn[m_][s + 32] : INT_MAX;
  const bool wr = (mbase + m_) < M;
  const size_t obase = (((size_t)b * M + (size_t)(mbase + m_)) * NSEG + sg) * (size_t)K;
  for (int r = 0; r < K; ++r) {
    float bv; int bn;
    if (v0 > v1 || (v0 == v1 && i0 < i1)) { bv = v0; bn = i0; } else { bv = v1; bn = i1; }
#pragma unroll
    for (int off = 16; off >= 1; off >>= 1) {
      float ov = __shfl_xor(bv, off);
      int on = __shfl_xor(bn, off);
      if (ov > bv || (ov == bv && on < bn)) { bv = ov; bn = on; }
    }
    if (s == 0 && wr) { gcv[obase + r] = bv; gci[obase + r] = bn; }
    if (bn == i0) { v0 = -FLT_MAX; i0 = INT_MAX; }
    if (bn == i1) { v1 = -FLT_MAX; i1 = INT_MAX; }
  }
}

// Phase 2: merge 26 sorted per-segment lists -> exact global top-20
// (v desc, n asc) -> softmax -> fused mvT gather -> outT[b][m][c].
__global__ __launch_bounds__(128) void merge_softmax_gather_kernel(
    const float* __restrict__ gcv, const int* __restrict__ gci,
    const float* __restrict__ mvT, float* __restrict__ outT) {
  const int m = blockIdx.x, b = blockIdx.y, t = threadIdx.x;
  __shared__ float lv[NSEG * K];
  __shared__ int   li[NSEG * K];
  __shared__ float wv[K];
  __shared__ int   wn[K];
  __shared__ float sw[K];
  const size_t base = ((size_t)b * M + m) * (size_t)(NSEG * K);
  for (int l = t; l < NSEG * K; l += 128) { lv[l] = gcv[base + l]; li[l] = gci[base + l]; }
  __syncthreads();

  if (t < 64) {
    const bool act = t < NSEG;
    int pos = 0;
    float hv = act ? lv[t * K] : -FLT_MAX;
    int   hn = act ? li[t * K] : INT_MAX;
    for (int r = 0; r < K; ++r) {
      float bv = hv; int bn = hn;
#pragma unroll
      for (int off = 16; off >= 1; off >>= 1) {
        float ov = __shfl_xor(bv, off);
        int on = __shfl_xor(bn, off);
        if (ov > bv || (ov == bv && on < bn)) { bv = ov; bn = on; }
      }
      if (t == 0) { wv[r] = bv; wn[r] = bn; }
      if (act && bn == hn) {
        ++pos;
        hv = (pos < K) ? lv[t * K + pos] : -FLT_MAX;
        hn = (pos < K) ? li[t * K + pos] : INT_MAX;
      }
    }
    // softmax over the 20 winners
    float v = (t < K) ? wv[t] : -FLT_MAX;
    float mx = v;
#pragma unroll
    for (int off = 1; off < 64; off <<= 1) mx = fmaxf(mx, __shfl_xor(mx, off));
    float e = (t < K) ? expf(v - mx) : 0.f;
    float ss = e;
#pragma unroll
    for (int off = 1; off < 64; off <<= 1) ss += __shfl_xor(ss, off);
    if (t < K) sw[t] = e / ss;
  }
  __syncthreads();

  if (t < CV / 4) {
    const float4* tb4 = reinterpret_cast<const float4*>(mvT + (size_t)b * N * CV);
    float4 acc = make_float4(0.f, 0.f, 0.f, 0.f);
#pragma unroll
    for (int j = 0; j < K; ++j) {
      const float wj = sw[j];
      const float4 v = tb4[(size_t)wn[j] * (CV / 4) + t];
      acc.x += wj * v.x; acc.y += wj * v.y; acc.z += wj * v.z; acc.w += wj * v.w;
    }
    reinterpret_cast<float4*>(outT + ((size_t)b * M + m) * CV)[t] = acc;
  }
}

}  // namespace

extern "C" void kernel_launch(void* const* d_in, const int* in_sizes, int n_in,
                              void* d_out, int out_size, void* d_ws, size_t ws_size,
                              hipStream_t stream) {
  const float* mk = (const float*)d_in[0];
  const float* qk = (const float*)d_in[1];
  const float* mv = (const float*)d_in[2];
  float* out = (float*)d_out;

  char* w = (char*)d_ws;
  float* asq = (float*)w;
  size_t o = (size_t)B * N * sizeof(float);              // 103,680 B
  float* mvT = (float*)(w + o);
  o += (size_t)B * N * CV * sizeof(float);               // +39,813,120 B
  float* outT = (float*)(w + o);
  o += (size_t)B * M * CV * sizeof(float);               // +4,976,640 B
  float* gcv = (float*)(w + o);
  o += (size_t)B * M * NSEG * K * sizeof(float);         // +6,739,200 B
  int* gci = (int*)(w + o);
  o += (size_t)B * M * NSEG * K * sizeof(int);           // +6,739,200 B  (~58 MB total)

  transpose_in_kernel<<<dim3((N + 63) / 64, CV / 64, B), 256, 0, stream>>>(mv, mvT, CV);
  asq_kernel<<<(B * N + 255) / 256, 256, 0, stream>>>(mk, asq);

  aff_seg_select_kernel<<<dim3(MTILES, NSEG, B), 512, 0, stream>>>(mk, qk, asq, gcv, gci);
  merge_softmax_gather_kernel<<<dim3(M, B), 128, 0, stream>>>(gcv, gci, mvT, outT);

  transpose_out_kernel<<<dim3((M + 63) / 64, CV / 64, B), 256, 0, stream>>>(outT, out);
}

// Round 8
// 475.999 us; speedup vs baseline: 1.0689x; 1.0689x over previous
//
#include <hip/hip_runtime.h>
#include <math.h>
#include <float.h>
#include <limits.h>
#include <stdint.h>

namespace {

constexpr int B  = 2;
constexpr int CK = 64;
constexpr int N  = 12960;   // T*H*W
constexpr int M  = 1620;    // H*W
constexpr int CV = 384;
constexpr int K  = 20;

constexpr int MT     = 16;                    // m per block
constexpr int SEG    = 512;                   // n per chunk (LDS-resident)
constexpr int NCH    = (N + SEG - 1) / SEG;   // 26 (last chunk = 160)
constexpr int MTILES = (M + MT - 1) / MT;     // 102
constexpr int AP     = SEG + 4;               // affL row pad (bank skew)
constexpr int SCAP   = 64;                    // survivor buffer per (m, chunk)

// strict lexicographic "better": value desc, index asc (lax.top_k tie order)
__device__ __forceinline__ bool lex_gt(float av, int an, float bv, int bn) {
  return (av > bv) || (av == bv && an < bn);
}

// [C][N] -> [N][C] transpose
__global__ __launch_bounds__(256) void transpose_in_kernel(const float* __restrict__ src,
                                                           float* __restrict__ dst, int C) {
  __shared__ float tile[64][65];
  int b = blockIdx.z;
  int n0 = blockIdx.x * 64;
  int c0 = blockIdx.y * 64;
  int tx = threadIdx.x & 63, ty = threadIdx.x >> 6;
  for (int r = ty; r < 64; r += 4) {
    int c = c0 + r, n = n0 + tx;
    tile[r][tx] = (n < N) ? src[((size_t)b * C + c) * N + n] : 0.f;
  }
  __syncthreads();
  for (int r = ty; r < 64; r += 4) {
    int n = n0 + r, c = c0 + tx;
    if (n < N) dst[((size_t)b * N + n) * C + c] = tile[tx][r];
  }
}

// out[b][c][m] = outT[b][m][c]
__global__ __launch_bounds__(256) void transpose_out_kernel(const float* __restrict__ outT,
                                                            float* __restrict__ out) {
  __shared__ float tile[64][65];
  int b = blockIdx.z;
  int m0 = blockIdx.x * 64;
  int c0 = blockIdx.y * 64;
  int tx = threadIdx.x & 63, ty = threadIdx.x >> 6;
  for (int r = ty; r < 64; r += 4) {
    int m = m0 + r;
    if (m < M) tile[r][tx] = outT[((size_t)b * M + m) * CV + c0 + tx];
  }
  __syncthreads();
  for (int r = ty; r < 64; r += 4) {
    int c = c0 + r, m = m0 + tx;
    if (m < M) out[((size_t)b * CV + c) * M + m] = tile[tx][r];
  }
}

// a_sq[b,n] = sum_c mk[b,c,n]^2
__global__ __launch_bounds__(256) void asq_kernel(const float* __restrict__ mk,
                                                  float* __restrict__ asq) {
  int i = blockIdx.x * 256 + threadIdx.x;
  if (i >= B * N) return;
  int b = i / N, n = i - b * N;
  const float* p = mk + (size_t)b * CK * N + n;
  float s = 0.f;
#pragma unroll
  for (int c = 0; c < CK; ++c) {
    float v = p[(size_t)c * N];
    s += v * v;
  }
  asq[i] = s;
}

// One block per (b, 16-m tile). Streams 26 n-chunks.
//   chunk 0 : exact per-m top-20 (per-lane bitonic + 20-round shfl merge)
//   chunk >0: tournament filter vs tau (broadcast via shfl from lane s==0).
//             Survivors go to an LDS buffer via ballot-prefix slots + VOLATILE
//             stores; lane s==0 alone merges them into the list (single-owner:
//             every list/tau access is same-thread -> no data race).
// Epilogue: softmax + fused mvT gather -> outT[b][m][c].
// Affinity FMA chain identical to all passing rounds -> identical selection.
__global__ __launch_bounds__(512, 2) void vos_fused_kernel(
    const float* __restrict__ mk, const float* __restrict__ qk,
    const float* __restrict__ asq, const float* __restrict__ mvT,
    float* __restrict__ outT) {
  const int b = blockIdx.y;
  const int mbase = blockIdx.x * MT;
  const int t = threadIdx.x;

  __shared__ float affL[MT][AP];        // 33 KB
  __shared__ float qs[CK][MT + 4];      // 5 KB
  __shared__ float list_v[MT][K];       // owned by lane s==0 of each group
  __shared__ int   list_n[MT][K];
  __shared__ float sw[MT][K];
  __shared__ float sbv[MT][SCAP];       // survivor buffer (volatile-accessed)
  __shared__ int   sbn[MT][SCAP];

  // stage qk tile once (m fixed for the whole block)
  for (int l = t; l < CK * MT; l += 512) {
    int c = l >> 4, ml = l & 15;
    int mg = mbase + ml;
    qs[c][ml] = (mg < M) ? qk[((size_t)b * CK + c) * M + mg] : 0.f;
  }
  __syncthreads();

  const int g    = t & 127;        // n float4-group within chunk
  const int mj   = (t >> 7) * 4;   // first of this thread's 4 m (wave-uniform)
  const int m_   = t >> 5;         // selection group (one m per 32 lanes)
  const int s    = t & 31;
  const int half = (t >> 5) & 1;   // which 32-lane half of the wave
  const uint32_t below = (1u << s) - 1u;   // s in [0,31]

  // tournament state: meaningful in lane s==0 only (broadcast via shfl)
  float tau_v = -FLT_MAX;
  int   tau_n = INT_MAX;
  int   targ  = K - 1;

  for (int ch = 0; ch < NCH; ++ch) {
    const int n0 = ch * SEG;
    const int segLen = min(SEG, N - n0);
    const int nl = 4 * g;
    const bool real = (nl < segLen);   // segLen % 4 == 0 -> all-or-nothing

    float4 r4[4];
    if (real) {
      const float* mkb = mk + (size_t)b * CK * N + n0 + nl;
      float4 a0 = make_float4(0.f, 0.f, 0.f, 0.f), a1 = a0, a2 = a0, a3 = a0;
#pragma unroll 8
      for (int c = 0; c < CK; ++c) {
        const float4 kv = *reinterpret_cast<const float4*>(mkb + (size_t)c * N);
        const float4 qv = *reinterpret_cast<const float4*>(&qs[c][mj]);
        a0.x += kv.x * qv.x; a0.y += kv.y * qv.x; a0.z += kv.z * qv.x; a0.w += kv.w * qv.x;
        a1.x += kv.x * qv.y; a1.y += kv.y * qv.y; a1.z += kv.z * qv.y; a1.w += kv.w * qv.y;
        a2.x += kv.x * qv.z; a2.y += kv.y * qv.z; a2.z += kv.z * qv.z; a2.w += kv.w * qv.z;
        a3.x += kv.x * qv.w; a3.y += kv.y * qv.w; a3.z += kv.z * qv.w; a3.w += kv.w * qv.w;
      }
      const float4 sq = *reinterpret_cast<const float4*>(asq + (size_t)b * N + n0 + nl);
      float4 accs[4] = {a0, a1, a2, a3};
#pragma unroll
      for (int j = 0; j < 4; ++j) {
        r4[j].x = (2.f * accs[j].x - sq.x) * 0.125f;
        r4[j].y = (2.f * accs[j].y - sq.y) * 0.125f;
        r4[j].z = (2.f * accs[j].z - sq.z) * 0.125f;
        r4[j].w = (2.f * accs[j].w - sq.w) * 0.125f;
      }
    } else {
      const float4 z = make_float4(-FLT_MAX, -FLT_MAX, -FLT_MAX, -FLT_MAX);
#pragma unroll
      for (int j = 0; j < 4; ++j) r4[j] = z;
    }
    __syncthreads();   // previous chunk's selection finished reading affL
#pragma unroll
    for (int j = 0; j < 4; ++j)
      *reinterpret_cast<float4*>(&affL[mj + j][nl]) = r4[j];
    __syncthreads();   // affL ready

    if (ch == 0) {
      // ---- bootstrap: exact top-20 of first 512 per m ----
      float v[16]; int nn[16];
#pragma unroll
      for (int j = 0; j < 16; ++j) {
        int nloc = s + 32 * j;
        v[j] = affL[m_][nloc];
        nn[j] = nloc;            // n0 == 0 here
      }
      // per-lane bitonic sort, best-first (lexicographic)
#pragma unroll
      for (int kk = 2; kk <= 16; kk <<= 1)
#pragma unroll
        for (int jj = kk >> 1; jj > 0; jj >>= 1)
#pragma unroll
          for (int i = 0; i < 16; ++i) {
            int l2 = i ^ jj;
            if (l2 > i) {
              bool up = ((i & kk) == 0);
              bool sw_ = up ? lex_gt(v[l2], nn[l2], v[i], nn[i])
                            : lex_gt(v[i], nn[i], v[l2], nn[l2]);
              if (sw_) {
                float tv_ = v[i]; v[i] = v[l2]; v[l2] = tv_;
                int tn_ = nn[i]; nn[i] = nn[l2]; nn[l2] = tn_;
              }
            }
          }
      // 20-round merge across 32 lanes (heads of sorted lists)
      float hv = v[0]; int hn = nn[0];
      float bv = -FLT_MAX; int bn = 0;
      for (int r = 0; r < K; ++r) {
        bv = hv; bn = hn;
#pragma unroll
        for (int off = 16; off >= 1; off >>= 1) {
          float ov = __shfl_xor(bv, off, 32);
          int on = __shfl_xor(bn, off, 32);
          if (lex_gt(ov, on, bv, bn)) { bv = ov; bn = on; }
        }
        if (s == 0) { list_v[m_][r] = bv; list_n[m_][r] = bn; }
        if (bn == hn) {  // I'm the winner: shift my sorted list down
#pragma unroll
          for (int i = 0; i < 15; ++i) { v[i] = v[i + 1]; nn[i] = nn[i + 1]; }
          v[15] = -FLT_MAX; nn[15] = INT_MAX;
          hv = v[0]; hn = nn[0];
        }
      }
      tau_v = bv; tau_n = bn; targ = K - 1;  // group-uniform; lane 0's copy rules
    } else {
      // ---- streaming tournament filter ----
      const float tvb = __shfl(tau_v, 0, 32);   // lane s==0 of this group
      const int   tnb = __shfl(tau_n, 0, 32);
      uint32_t flags = 0;
#pragma unroll
      for (int j = 0; j < 16; ++j) {
        int nloc = s + 32 * j;
        float x = affL[m_][nloc];
        if (lex_gt(x, n0 + nloc, tvb, tnb)) flags |= (1u << j);
      }
      while (true) {
        uint64_t anyb = __ballot(flags != 0u);
        uint32_t gany = half ? (uint32_t)(anyb >> 32) : (uint32_t)anyb;
        if (gany == 0u) break;
        // slot survivors via ballot prefix-popcount; VOLATILE stores
        int base = 0;
        uint32_t stored = 0u;
        for (int j = 0; j < 16; ++j) {
          const bool has = (flags >> j) & 1u;
          uint64_t bj = __ballot(has);
          uint32_t gbj = half ? (uint32_t)(bj >> 32) : (uint32_t)bj;
          if (has) {
            int slot = base + __popc(gbj & below);
            if (slot < SCAP) {
              int nloc = s + 32 * j;
              *(volatile float*)&sbv[m_][slot] = affL[m_][nloc];
              *(volatile int*)&sbn[m_][slot] = n0 + nloc;
              stored |= (1u << j);
            }
          }
          base += __popc(gbj);
        }
        flags &= ~stored;
        const int nr = min(base, SCAP);
        if (s == 0) {
          // single-owner merge: all list/tau accesses are same-thread
          for (int r = 0; r < nr; ++r) {
            float x = *(volatile float*)&sbv[m_][r];
            int n = *(volatile int*)&sbn[m_][r];
            if (lex_gt(x, n, tau_v, tau_n)) {
              list_v[m_][targ] = x; list_n[m_][targ] = n;
              float wv_ = list_v[m_][0]; int wn_ = list_n[m_][0]; int wa_ = 0;
#pragma unroll
              for (int i2 = 1; i2 < K; ++i2) {
                float cv2 = list_v[m_][i2]; int cn2 = list_n[m_][i2];
                if (lex_gt(wv_, wn_, cv2, cn2)) { wv_ = cv2; wn_ = cn2; wa_ = i2; }
              }
              tau_v = wv_; tau_n = wn_; targ = wa_;
            }
          }
        }
        if (base <= SCAP) break;   // group-uniform
        // overflow (rare): re-filter remaining vs updated tau
        const float tv2 = __shfl(tau_v, 0, 32);
        const int tn2 = __shfl(tau_n, 0, 32);
        uint32_t nf = 0u;
        for (int j = 0; j < 16; ++j) {
          if ((flags >> j) & 1u) {
            int nloc = s + 32 * j;
            float x = affL[m_][nloc];
            if (lex_gt(x, n0 + nloc, tv2, tn2)) nf |= (1u << j);
          }
        }
        flags = nf;
      }
    }
  }
  __syncthreads();   // lane-0 lists visible to all

  // ---- softmax over each m's 20 winners (one 32-lane group per m) ----
  {
    float val = (s < K) ? list_v[m_][s] : -FLT_MAX;
    float mx = val;
#pragma unroll
    for (int off = 16; off >= 1; off >>= 1) mx = fmaxf(mx, __shfl_xor(mx, off, 32));
    float e = (s < K) ? expf(val - mx) : 0.f;
    float ssum = e;
#pragma unroll
    for (int off = 16; off >= 1; off >>= 1) ssum += __shfl_xor(ssum, off, 32);
    if (s < K) sw[m_][s] = e / ssum;
  }
  __syncthreads();

  // ---- fused gather: outT[b][m][c] = sum_j sw[j] * mvT[b][n_j][c] ----
  const int mg = mbase + m_;
  if (mg < M) {
    const float4* tb4 = reinterpret_cast<const float4*>(mvT + (size_t)b * N * CV);
    float4* orow = reinterpret_cast<float4*>(outT + ((size_t)b * M + mg) * CV);
#pragma unroll
    for (int sl = 0; sl < 3; ++sl) {   // 96 float4 slots / 32 lanes
      int c4 = s + 32 * sl;
      float4 acc = make_float4(0.f, 0.f, 0.f, 0.f);
#pragma unroll
      for (int j = 0; j < K; ++j) {
        float wj = sw[m_][j];
        float4 vv = tb4[(size_t)list_n[m_][j] * (CV / 4) + c4];
        acc.x += wj * vv.x; acc.y += wj * vv.y; acc.z += wj * vv.z; acc.w += wj * vv.w;
      }
      orow[c4] = acc;
    }
  }
}

}  // namespace

extern "C" void kernel_launch(void* const* d_in, const int* in_sizes, int n_in,
                              void* d_out, int out_size, void* d_ws, size_t ws_size,
                              hipStream_t stream) {
  const float* mk = (const float*)d_in[0];
  const float* qk = (const float*)d_in[1];
  const float* mv = (const float*)d_in[2];
  float* out = (float*)d_out;

  char* w = (char*)d_ws;
  float* asq = (float*)w;
  size_t o = (size_t)B * N * sizeof(float);              // 103,680 B
  float* mvT = (float*)(w + o);
  o += (size_t)B * N * CV * sizeof(float);               // +39,813,120 B
  float* outT = (float*)(w + o);
  o += (size_t)B * M * CV * sizeof(float);               // +4,976,640 B (~45 MB total)

  transpose_in_kernel<<<dim3((N + 63) / 64, CV / 64, B), 256, 0, stream>>>(mv, mvT, CV);
  asq_kernel<<<(B * N + 255) / 256, 256, 0, stream>>>(mk, asq);

  vos_fused_kernel<<<dim3(MTILES, B), 512, 0, stream>>>(mk, qk, asq, mvT, outT);

  transpose_out_kernel<<<dim3((M + 63) / 64, CV / 64, B), 256, 0, stream>>>(outT, out);
}